// Round 7
// baseline (275.962 us; speedup 1.0000x reference)
//
#include <hip/hip_runtime.h>

#define NQ 11
#define NGD 300
#define NS 10

typedef float v2f __attribute__((ext_vector_type(2)));

// Per-pixel independent GD fit: x=(A,Bp,R1), model s_q = A - Bp*exp(-tau_q*R1).
// Denoiser/lm/NaN-scrub in reference are dead code (Dx=clip(x)==x).
// R6->R7: hypothesis = trans pipe (v_exp_f32, ~32cyc/wave) is the saturated
// resource, not VALU issue. Move 6 of 11 exps to a packed-f32 polynomial exp2
// (magic-const range reduction, deg-5 Horner via v_pk_fma_f32, integer exponent
// add). Balances VALU vs trans pipe. Early exit removed (never fired R5/R6).

__device__ __forceinline__ float fexp2(float x) {
#if __has_builtin(__builtin_amdgcn_exp2f)
    return __builtin_amdgcn_exp2f(x);
#else
    float r; asm("v_exp_f32 %0, %1" : "=v"(r) : "v"(x)); return r;
#endif
}
__device__ __forceinline__ float clampm(float x, float lo, float hi) {
#if __has_builtin(__builtin_amdgcn_fmed3f)
    return __builtin_amdgcn_fmed3f(x, lo, hi);
#else
    return fminf(fmaxf(x, lo), hi);
#endif
}

// packed exp2 via VALU only (no trans pipe):
// n = RN(x) via magic const; f = x - n in [-0.5,0.5] (exact);
// exp2(f) = deg-5 Taylor-in-(f ln2), rel err ~3.4e-6;
// scale by 2^n: result_bits = poly_bits + (t_bits << 23)
// (t = magic + n; low 9 bits of magic are 0 so (t_bits<<23) == n<<23).
// x clamped at -120 so exponent never wraps (true exp2(-120)=7.5e-37 ~ 0).
__device__ __forceinline__ v2f pexp2(v2f x) {
    const float MG = 12582912.0f;  // 1.5 * 2^23
    x = __builtin_elementwise_max(x, (v2f){-120.0f, -120.0f});
    v2f t = x + (v2f){MG, MG};
    v2f n = t - (v2f){MG, MG};
    v2f f = x - n;
    v2f p = (v2f){0.00133335581464f, 0.00133335581464f};
    p = __builtin_elementwise_fma(p, f, (v2f){0.00961812910763f, 0.00961812910763f});
    p = __builtin_elementwise_fma(p, f, (v2f){0.0555041086648f, 0.0555041086648f});
    p = __builtin_elementwise_fma(p, f, (v2f){0.240226506959f, 0.240226506959f});
    p = __builtin_elementwise_fma(p, f, (v2f){0.693147180560f, 0.693147180560f});
    p = __builtin_elementwise_fma(p, f, (v2f){1.0f, 1.0f});
    union { v2f v; unsigned int u[2]; } tb, pb, rb;
    tb.v = t; pb.v = p;
    rb.u[0] = pb.u[0] + (tb.u[0] << 23);   // v_lshl_add_u32
    rb.u[1] = pb.u[1] + (tb.u[1] << 23);
    return rb.v;
}

__global__ __launch_bounds__(128) void dop_fit_kernel(
    const float* __restrict__ b,    // [P][NQ]
    const float* __restrict__ tau,  // [NQ]
    const float* __restrict__ mu,   // [NS]
    float* __restrict__ out,        // [2+NS][P][3]
    int P)
{
    const int p = blockIdx.x * blockDim.x + threadIdx.x;
    if (p >= P) return;

    const float LOG2E = 1.44269504088896340736f;

    float bq[NQ];
#pragma unroll
    for (int q = 0; q < NQ; ++q) bq[q] = b[(size_t)p * NQ + q];

    v2f tq2[5], ct2[5], nb2[5];
#pragma unroll
    for (int j = 0; j < 5; ++j) {
        float t0 = tau[2 * j], t1 = tau[2 * j + 1];   // uniform -> s_load
        tq2[j] = (v2f){t0, t1};
        ct2[j] = (v2f){-t0 * LOG2E, -t1 * LOG2E};
        nb2[j] = (v2f){-bq[2 * j], -bq[2 * j + 1]};
    }
    const float t10 = tau[10];
    const float ct10 = -t10 * LOG2E;
    const float nb10 = -bq[10];

    float A = 0.0f;
#pragma unroll
    for (int q = 0; q < NQ; ++q) A = fmaxf(A, fabsf(bq[q]));

    float xA = fminf(A, 3.0f);
    float xB = fminf(2.0f * A, 6.0f);
    float xR = 1.0f;

    const size_t stride = (size_t)P * 3u;
    size_t o = (size_t)p * 3u;
    out[o + 0] = xA; out[o + 1] = xB; out[o + 2] = xR;

    const float inv11 = 1.0f / 11.0f;

    auto step = [&](float a) {
        // ---- phase 1: all exponentials (mixed pipes) ----
        v2f e2[5];
        e2[0] = pexp2(ct2[0] * xR);                  // VALU poly
        e2[1] = pexp2(ct2[1] * xR);                  // VALU poly
        e2[2] = pexp2(ct2[2] * xR);                  // VALU poly
        {
            v2f m3 = ct2[3] * xR, m4 = ct2[4] * xR;  // trans pipe
            e2[3].x = fexp2(m3.x); e2[3].y = fexp2(m3.y);
            e2[4].x = fexp2(m4.x); e2[4].y = fexp2(m4.y);
        }
        float e10 = fexp2(ct10 * xR);                // trans pipe

        // ---- phase 2: accumulate ----
        v2f sA2 = (v2f){0.f, 0.f}, sE2 = (v2f){0.f, 0.f}, sT2 = (v2f){0.f, 0.f};
        const v2f xA2  = (v2f){xA, xA};
        const v2f nxB2 = (v2f){-xB, -xB};
#pragma unroll
        for (int j = 0; j < 5; ++j) {
            v2f r2 = __builtin_elementwise_fma(nxB2, e2[j], xA2) + nb2[j];
            sA2 += r2;
            v2f re2 = r2 * e2[j];
            sE2 += re2;
            sT2 = __builtin_elementwise_fma(re2, tq2[j], sT2);
        }
        float r10  = fmaf(-xB, e10, xA) + nb10;
        float re10 = r10 * e10;

        // ---- phase 3: merge + update (xR first: next step's exps depend on it) ----
        float sA = (sA2.x + sA2.y) + r10;
        float sE = (sE2.x + sE2.y) + re10;
        float sT = fmaf(re10, t10, sT2.x + sT2.y);
        float mR = a * xB;                            // old xB
        xR = clampm(fmaf(-mR, sT, xR), 0.0f, 50.0f);
        xA = clampm(fmaf(-a,  sA, xA), 0.0f, 3.0f);
        xB = clampm(fmaf( a,  sE, xB), 0.0f, 6.0f);
    };

    const float aGD = 2.0f * inv11;
    for (int it = 0; it < NGD; ++it) step(aGD);

    o += stride;
    out[o + 0] = xA; out[o + 1] = xB; out[o + 2] = xR;

    for (int i = 0; i < NS; ++i) {
        step(mu[i] * inv11);
        o += stride;
        out[o + 0] = xA; out[o + 1] = xB; out[o + 2] = xR;
    }
}

extern "C" void kernel_launch(void* const* d_in, const int* in_sizes, int n_in,
                              void* d_out, int out_size, void* d_ws, size_t ws_size,
                              hipStream_t stream) {
    const float* b   = (const float*)d_in[0];  // (8,192,192,11)
    const float* tau = (const float*)d_in[1];  // (1,11)
    const float* mu  = (const float*)d_in[2];  // (10,)
    float* out = (float*)d_out;                // (12, 8, 192, 192, 3) f32

    const int P = in_sizes[0] / NQ;            // 294912
    const int block = 128;
    const int grid = (P + block - 1) / block;  // 2304 wg = 9 wg/CU exactly
    dop_fit_kernel<<<grid, block, 0, stream>>>(b, tau, mu, out, P);
}

// Round 9
// 266.046 us; speedup vs baseline: 1.0373x; 1.0373x over previous
//
#include <hip/hip_runtime.h>

#define NQ 11
#define NGD 300
#define NS 10

typedef float v2f __attribute__((ext_vector_type(2)));
typedef __fp16 h2v __attribute__((ext_vector_type(2)));

// Per-pixel independent GD fit: x=(A,Bp,R1), model s_q = A - Bp*exp(-tau_q*R1).
// Denoiser/lm/NaN-scrub in reference are dead code (Dx=clip(x)==x).
// R8->R9: same discriminating experiment as R8 (v_exp_f16 vs v_exp_f32 trans
// rate), compile error fixed: cvt_pkrtz builtin returns __fp16 vector.
// Model from R1-R7: busy/step = waves x (VALU ~150cyc + 11 exps x ~16cyc)
// serialized; VALUBusy 79% matches R6 exactly. If f16 trans is double-rate,
// expect ~ -18%; if same-rate, mild regression and R6 is the established floor.
// Accuracy: f16 arg rounding -> ~1e-3 rel err on e; m in [-216,0] fits f16;
// f16 underflow->0 harmless (true e < 6e-8 contributes nothing to grads).

__device__ __forceinline__ float clampm(float x, float lo, float hi) {
#if __has_builtin(__builtin_amdgcn_fmed3f)
    return __builtin_amdgcn_fmed3f(x, lo, hi);
#else
    return fminf(fmaxf(x, lo), hi);
#endif
}

// packed f32 pair -> f16 exp2 -> f32 pair
__device__ __forceinline__ v2f hexp2pair(v2f m) {
    h2v hm = __builtin_amdgcn_cvt_pkrtz(m.x, m.y);   // v_cvt_pkrtz_f16_f32
    __fp16 e0, e1;
    asm("v_exp_f16 %0, %1" : "=v"(e0) : "v"(hm.x));
    asm("v_exp_f16 %0, %1" : "=v"(e1) : "v"(hm.y));
    return (v2f){(float)e0, (float)e1};              // 2x v_cvt_f32_f16
}
__device__ __forceinline__ float hexp2s(float m) {
    __fp16 hm = (__fp16)m, e;
    asm("v_exp_f16 %0, %1" : "=v"(e) : "v"(hm));
    return (float)e;
}

__global__ __launch_bounds__(128) void dop_fit_kernel(
    const float* __restrict__ b,    // [P][NQ]
    const float* __restrict__ tau,  // [NQ]
    const float* __restrict__ mu,   // [NS]
    float* __restrict__ out,        // [2+NS][P][3]
    int P)
{
    const int p = blockIdx.x * blockDim.x + threadIdx.x;
    if (p >= P) return;

    const float LOG2E = 1.44269504088896340736f;

    float bq[NQ];
#pragma unroll
    for (int q = 0; q < NQ; ++q) bq[q] = b[(size_t)p * NQ + q];

    v2f tq2[5], ct2[5], nb2[5];
#pragma unroll
    for (int j = 0; j < 5; ++j) {
        float t0 = tau[2 * j], t1 = tau[2 * j + 1];   // uniform -> s_load
        tq2[j] = (v2f){t0, t1};
        ct2[j] = (v2f){-t0 * LOG2E, -t1 * LOG2E};
        nb2[j] = (v2f){-bq[2 * j], -bq[2 * j + 1]};
    }
    const float t10 = tau[10];
    const float ct10 = -t10 * LOG2E;
    const float nb10 = -bq[10];

    float A = 0.0f;
#pragma unroll
    for (int q = 0; q < NQ; ++q) A = fmaxf(A, fabsf(bq[q]));

    float xA = fminf(A, 3.0f);
    float xB = fminf(2.0f * A, 6.0f);
    float xR = 1.0f;

    const size_t stride = (size_t)P * 3u;
    size_t o = (size_t)p * 3u;
    out[o + 0] = xA; out[o + 1] = xB; out[o + 2] = xR;

    const float inv11 = 1.0f / 11.0f;

    auto step = [&](float a) {
        v2f sA2 = (v2f){0.f, 0.f}, sE2 = (v2f){0.f, 0.f}, sT2 = (v2f){0.f, 0.f};
        const v2f xA2  = (v2f){xA, xA};
        const v2f nxB2 = (v2f){-xB, -xB};
#pragma unroll
        for (int j = 0; j < 5; ++j) {
            v2f e2 = hexp2pair(ct2[j] * xR);                        // f16 trans
            v2f r2 = __builtin_elementwise_fma(nxB2, e2, xA2) + nb2[j];
            sA2 += r2;
            v2f re2 = r2 * e2;
            sE2 += re2;
            sT2 = __builtin_elementwise_fma(re2, tq2[j], sT2);
        }
        float e  = hexp2s(ct10 * xR);
        float r  = fmaf(-xB, e, xA) + nb10;
        float re = r * e;
        float sA = (sA2.x + sA2.y) + r;
        float sE = (sE2.x + sE2.y) + re;
        float sT = fmaf(re, t10, sT2.x + sT2.y);
        float mR = a * xB;                                          // old xB
        xR = clampm(fmaf(-mR, sT, xR), 0.0f, 50.0f);                // xR first: next exps need it
        xA = clampm(fmaf(-a,  sA, xA), 0.0f, 3.0f);
        xB = clampm(fmaf( a,  sE, xB), 0.0f, 6.0f);
    };

    const float aGD = 2.0f * inv11;
    for (int it = 0; it < NGD; ++it) step(aGD);

    o += stride;
    out[o + 0] = xA; out[o + 1] = xB; out[o + 2] = xR;

    for (int i = 0; i < NS; ++i) {
        step(mu[i] * inv11);
        o += stride;
        out[o + 0] = xA; out[o + 1] = xB; out[o + 2] = xR;
    }
}

extern "C" void kernel_launch(void* const* d_in, const int* in_sizes, int n_in,
                              void* d_out, int out_size, void* d_ws, size_t ws_size,
                              hipStream_t stream) {
    const float* b   = (const float*)d_in[0];  // (8,192,192,11)
    const float* tau = (const float*)d_in[1];  // (1,11)
    const float* mu  = (const float*)d_in[2];  // (10,)
    float* out = (float*)d_out;                // (12, 8, 192, 192, 3) f32

    const int P = in_sizes[0] / NQ;            // 294912
    const int block = 128;
    const int grid = (P + block - 1) / block;  // 2304 wg = 9 wg/CU exactly
    dop_fit_kernel<<<grid, block, 0, stream>>>(b, tau, mu, out, P);
}

// Round 10
// 206.498 us; speedup vs baseline: 1.3364x; 1.2884x over previous
//
#include <hip/hip_runtime.h>

#define NQ 11
#define NGD 300
#define NS 10

typedef float v2f __attribute__((ext_vector_type(2)));

// Per-pixel independent GD fit: x=(A,Bp,R1), model s_q = A - Bp*exp(-tau_q*R1).
// Denoiser/lm/NaN-scrub in reference are dead code (Dx=clip(x)==x).
// R9->R10: trans-pipe burst scheduling. Math IDENTICAL to R6 (best, 240us
// rocprof); only instruction ORDER changes: all 11 v_exp_f32 issued
// back-to-back (phase 1) before any accumulation (phase 2), so the trans pipe
// drains while VALU accumulates — tests whether R6's 21% idle is in-wave
// exp/VALU phase collision. Plus #pragma unroll 2 on the GD loop.
// f16 exp (R9: same trans rate + cvt cost) and VALU poly (R7) both refuted.

__device__ __forceinline__ float fexp2(float x) {
#if __has_builtin(__builtin_amdgcn_exp2f)
    return __builtin_amdgcn_exp2f(x);
#else
    float r; asm("v_exp_f32 %0, %1" : "=v"(r) : "v"(x)); return r;
#endif
}
__device__ __forceinline__ float clampm(float x, float lo, float hi) {
#if __has_builtin(__builtin_amdgcn_fmed3f)
    return __builtin_amdgcn_fmed3f(x, lo, hi);
#else
    return fminf(fmaxf(x, lo), hi);
#endif
}

__global__ __launch_bounds__(128) void dop_fit_kernel(
    const float* __restrict__ b,    // [P][NQ]
    const float* __restrict__ tau,  // [NQ]
    const float* __restrict__ mu,   // [NS]
    float* __restrict__ out,        // [2+NS][P][3]
    int P)
{
    const int p = blockIdx.x * blockDim.x + threadIdx.x;
    if (p >= P) return;

    const float LOG2E = 1.44269504088896340736f;

    float bq[NQ];
#pragma unroll
    for (int q = 0; q < NQ; ++q) bq[q] = b[(size_t)p * NQ + q];

    v2f tq2[5], ct2[5], nb2[5];
#pragma unroll
    for (int j = 0; j < 5; ++j) {
        float t0 = tau[2 * j], t1 = tau[2 * j + 1];   // uniform -> s_load
        tq2[j] = (v2f){t0, t1};
        ct2[j] = (v2f){-t0 * LOG2E, -t1 * LOG2E};
        nb2[j] = (v2f){-bq[2 * j], -bq[2 * j + 1]};
    }
    const float t10 = tau[10];
    const float ct10 = -t10 * LOG2E;
    const float nb10 = -bq[10];

    float A = 0.0f;
#pragma unroll
    for (int q = 0; q < NQ; ++q) A = fmaxf(A, fabsf(bq[q]));

    float xA = fminf(A, 3.0f);
    float xB = fminf(2.0f * A, 6.0f);
    float xR = 1.0f;

    const size_t stride = (size_t)P * 3u;
    size_t o = (size_t)p * 3u;
    out[o + 0] = xA; out[o + 1] = xB; out[o + 2] = xR;

    const float inv11 = 1.0f / 11.0f;

    auto step = [&](float a) {
        // ---- phase 1: all 11 exponentials issued back-to-back ----
        v2f m0 = ct2[0] * xR, m1 = ct2[1] * xR, m2 = ct2[2] * xR,
            m3 = ct2[3] * xR, m4 = ct2[4] * xR;
        float m10 = ct10 * xR;
        v2f e2[5];
        float e10;
        e2[0].x = fexp2(m0.x); e2[0].y = fexp2(m0.y);
        e2[1].x = fexp2(m1.x); e2[1].y = fexp2(m1.y);
        e2[2].x = fexp2(m2.x); e2[2].y = fexp2(m2.y);
        e2[3].x = fexp2(m3.x); e2[3].y = fexp2(m3.y);
        e2[4].x = fexp2(m4.x); e2[4].y = fexp2(m4.y);
        e10 = fexp2(m10);

        // ---- phase 2: accumulate (VALU overlaps trans drain) ----
        v2f sA2 = (v2f){0.f, 0.f}, sE2 = (v2f){0.f, 0.f}, sT2 = (v2f){0.f, 0.f};
        const v2f xA2  = (v2f){xA, xA};
        const v2f nxB2 = (v2f){-xB, -xB};
#pragma unroll
        for (int j = 0; j < 5; ++j) {
            v2f r2 = __builtin_elementwise_fma(nxB2, e2[j], xA2) + nb2[j];
            sA2 += r2;
            v2f re2 = r2 * e2[j];
            sE2 += re2;
            sT2 = __builtin_elementwise_fma(re2, tq2[j], sT2);
        }
        float r10  = fmaf(-xB, e10, xA) + nb10;
        float re10 = r10 * e10;

        // ---- phase 3: merge + update (xR first: next step's exps need it) ----
        float sA = (sA2.x + sA2.y) + r10;
        float sE = (sE2.x + sE2.y) + re10;
        float sT = fmaf(re10, t10, sT2.x + sT2.y);
        float mR = a * xB;                            // old xB
        xR = clampm(fmaf(-mR, sT, xR), 0.0f, 50.0f);
        xA = clampm(fmaf(-a,  sA, xA), 0.0f, 3.0f);
        xB = clampm(fmaf( a,  sE, xB), 0.0f, 6.0f);
    };

    const float aGD = 2.0f * inv11;
#pragma unroll 2
    for (int it = 0; it < NGD; ++it) step(aGD);

    o += stride;
    out[o + 0] = xA; out[o + 1] = xB; out[o + 2] = xR;

    for (int i = 0; i < NS; ++i) {
        step(mu[i] * inv11);
        o += stride;
        out[o + 0] = xA; out[o + 1] = xB; out[o + 2] = xR;
    }
}

extern "C" void kernel_launch(void* const* d_in, const int* in_sizes, int n_in,
                              void* d_out, int out_size, void* d_ws, size_t ws_size,
                              hipStream_t stream) {
    const float* b   = (const float*)d_in[0];  // (8,192,192,11)
    const float* tau = (const float*)d_in[1];  // (1,11)
    const float* mu  = (const float*)d_in[2];  // (10,)
    float* out = (float*)d_out;                // (12, 8, 192, 192, 3) f32

    const int P = in_sizes[0] / NQ;            // 294912
    const int block = 128;
    const int grid = (P + block - 1) / block;  // 2304 wg = 9 wg/CU exactly
    dop_fit_kernel<<<grid, block, 0, stream>>>(b, tau, mu, out, P);
}

// Round 13
// 206.285 us; speedup vs baseline: 1.3378x; 1.0010x over previous
//
#include <hip/hip_runtime.h>

#define NQ 11
#define NGD 300
#define NS 10

typedef float v2f __attribute__((ext_vector_type(2)));

// Per-pixel independent GD fit: x=(A,Bp,R1), model s_q = A - Bp*exp(-tau_q*R1).
// Denoiser/lm/NaN-scrub in reference are dead code (Dx=clip(x)==x).
// R12->R13: REVERT to R10 (best passing: 206us bench / 235us rocprof).
// Forced v_pk_*_f32 inline asm (R11/R12) produced corrupted results even with
// explicit op_sel -- consistent with CDNA packed-f32 hazard wait-states that
// the compiler can't insert around opaque asm; lever abandoned.
// Established floor model: issue-serialized, 4.5 waves/SIMD x
// (~89 VALU slots x 2cyc + 11 v_exp_f32 x ~16cyc) ~= 1600 cyc/step modeled
// vs 1820 measured (VALUBusy 79%, residual = dep-chain latency; wave count
// is problem-size-capped). Refuted levers: 2px/thread (R5), VALU-poly exp
// (R7), f16 exp (R9), early exits (R3/R5/R6 -- never fire), pk-f32 (R11/12).

__device__ __forceinline__ float fexp2(float x) {
#if __has_builtin(__builtin_amdgcn_exp2f)
    return __builtin_amdgcn_exp2f(x);
#else
    float r; asm("v_exp_f32 %0, %1" : "=v"(r) : "v"(x)); return r;
#endif
}
__device__ __forceinline__ float clampm(float x, float lo, float hi) {
#if __has_builtin(__builtin_amdgcn_fmed3f)
    return __builtin_amdgcn_fmed3f(x, lo, hi);
#else
    return fminf(fmaxf(x, lo), hi);
#endif
}

__global__ __launch_bounds__(128) void dop_fit_kernel(
    const float* __restrict__ b,    // [P][NQ]
    const float* __restrict__ tau,  // [NQ]
    const float* __restrict__ mu,   // [NS]
    float* __restrict__ out,        // [2+NS][P][3]
    int P)
{
    const int p = blockIdx.x * blockDim.x + threadIdx.x;
    if (p >= P) return;

    const float LOG2E = 1.44269504088896340736f;

    float bq[NQ];
#pragma unroll
    for (int q = 0; q < NQ; ++q) bq[q] = b[(size_t)p * NQ + q];

    v2f tq2[5], ct2[5], nb2[5];
#pragma unroll
    for (int j = 0; j < 5; ++j) {
        float t0 = tau[2 * j], t1 = tau[2 * j + 1];   // uniform -> s_load
        tq2[j] = (v2f){t0, t1};
        ct2[j] = (v2f){-t0 * LOG2E, -t1 * LOG2E};
        nb2[j] = (v2f){-bq[2 * j], -bq[2 * j + 1]};
    }
    const float t10 = tau[10];
    const float ct10 = -t10 * LOG2E;
    const float nb10 = -bq[10];

    float A = 0.0f;
#pragma unroll
    for (int q = 0; q < NQ; ++q) A = fmaxf(A, fabsf(bq[q]));

    float xA = fminf(A, 3.0f);
    float xB = fminf(2.0f * A, 6.0f);
    float xR = 1.0f;

    const size_t stride = (size_t)P * 3u;
    size_t o = (size_t)p * 3u;
    out[o + 0] = xA; out[o + 1] = xB; out[o + 2] = xR;

    const float inv11 = 1.0f / 11.0f;

    auto step = [&](float a) {
        // ---- phase 1: all 11 exponentials issued back-to-back ----
        v2f m0 = ct2[0] * xR, m1 = ct2[1] * xR, m2 = ct2[2] * xR,
            m3 = ct2[3] * xR, m4 = ct2[4] * xR;
        float m10 = ct10 * xR;
        v2f e2[5];
        float e10;
        e2[0].x = fexp2(m0.x); e2[0].y = fexp2(m0.y);
        e2[1].x = fexp2(m1.x); e2[1].y = fexp2(m1.y);
        e2[2].x = fexp2(m2.x); e2[2].y = fexp2(m2.y);
        e2[3].x = fexp2(m3.x); e2[3].y = fexp2(m3.y);
        e2[4].x = fexp2(m4.x); e2[4].y = fexp2(m4.y);
        e10 = fexp2(m10);

        // ---- phase 2: accumulate (VALU overlaps trans drain) ----
        v2f sA2 = (v2f){0.f, 0.f}, sE2 = (v2f){0.f, 0.f}, sT2 = (v2f){0.f, 0.f};
        const v2f xA2  = (v2f){xA, xA};
        const v2f nxB2 = (v2f){-xB, -xB};
#pragma unroll
        for (int j = 0; j < 5; ++j) {
            v2f r2 = __builtin_elementwise_fma(nxB2, e2[j], xA2) + nb2[j];
            sA2 += r2;
            v2f re2 = r2 * e2[j];
            sE2 += re2;
            sT2 = __builtin_elementwise_fma(re2, tq2[j], sT2);
        }
        float r10  = fmaf(-xB, e10, xA) + nb10;
        float re10 = r10 * e10;

        // ---- phase 3: merge + update (xR first: next step's exps need it) ----
        float sA = (sA2.x + sA2.y) + r10;
        float sE = (sE2.x + sE2.y) + re10;
        float sT = fmaf(re10, t10, sT2.x + sT2.y);
        float mR = a * xB;                            // old xB
        xR = clampm(fmaf(-mR, sT, xR), 0.0f, 50.0f);
        xA = clampm(fmaf(-a,  sA, xA), 0.0f, 3.0f);
        xB = clampm(fmaf( a,  sE, xB), 0.0f, 6.0f);
    };

    const float aGD = 2.0f * inv11;
#pragma unroll 2
    for (int it = 0; it < NGD; ++it) step(aGD);

    o += stride;
    out[o + 0] = xA; out[o + 1] = xB; out[o + 2] = xR;

    for (int i = 0; i < NS; ++i) {
        step(mu[i] * inv11);
        o += stride;
        out[o + 0] = xA; out[o + 1] = xB; out[o + 2] = xR;
    }
}

extern "C" void kernel_launch(void* const* d_in, const int* in_sizes, int n_in,
                              void* d_out, int out_size, void* d_ws, size_t ws_size,
                              hipStream_t stream) {
    const float* b   = (const float*)d_in[0];  // (8,192,192,11)
    const float* tau = (const float*)d_in[1];  // (1,11)
    const float* mu  = (const float*)d_in[2];  // (10,)
    float* out = (float*)d_out;                // (12, 8, 192, 192, 3) f32

    const int P = in_sizes[0] / NQ;            // 294912
    const int block = 128;
    const int grid = (P + block - 1) / block;  // 2304 wg = 9 wg/CU exactly
    dop_fit_kernel<<<grid, block, 0, stream>>>(b, tau, mu, out, P);
}